// Round 8
// baseline (58521.765 us; speedup 1.0000x reference)
//
#include <hip/hip_runtime.h>
#include <stdint.h>
#include <stddef.h>

#define T_STEPS 512
#define B_SZ    128
#define DIN     1024
#define H_SZ    2048
#define NG      8192            // 4*H
#define BH      (B_SZ * H_SZ)   // 262144

typedef __attribute__((ext_vector_type(8))) short bf16x8;
typedef __attribute__((ext_vector_type(4))) float f32x4;

static __device__ __forceinline__ unsigned short f2bf(float x) {
  unsigned int u = __float_as_uint(x);
  u += 0x7fffu + ((u >> 16) & 1u);   // RNE; inputs finite
  return (unsigned short)(u >> 16);
}

static __device__ __forceinline__ float sigm(float x) {
  return 1.0f / (1.0f + __expf(-x));
}
static __device__ __forceinline__ float tanh_(float x) {
  float e = __expf(-2.0f * fabsf(x));  // in (0,1], no overflow
  float t = (1.0f - e) / (1.0f + e);
  return x < 0.0f ? -t : t;
}

// global -> LDS async copy, 16B per lane. LDS dest is wave-uniform base;
// HW writes lane l at ldst + l*16 (masked lanes skip). Global src per-lane.
static __device__ __forceinline__ void async_load16(const void* gsrc, void* ldst) {
  __builtin_amdgcn_global_load_lds(
      (__attribute__((address_space(1))) void*)(const_cast<void*>(gsrc)),
      (__attribute__((address_space(3))) void*)ldst,
      16, 0, 0);
}

// Barrier that memory ops cannot be compiler-moved across (rd4's NaN fix).
static __device__ __forceinline__ void wg_barrier_pinned() {
  __builtin_amdgcn_s_barrier();
  asm volatile("" ::: "memory");
  __builtin_amdgcn_sched_barrier(0);
}

__global__ void cvt_x_bf16(const float4* __restrict__ in, ushort4* __restrict__ out, int n4) {
  int i = blockIdx.x * blockDim.x + threadIdx.x;
  int st = gridDim.x * blockDim.x;
  for (; i < n4; i += st) {
    float4 v = in[i];
    ushort4 o;
    o.x = f2bf(v.x); o.y = f2bf(v.y); o.z = f2bf(v.z); o.w = f2bf(v.w);
    out[i] = o;
  }
}

__global__ void build_wcat(const float* __restrict__ wa, const float* __restrict__ wb,
                           unsigned short* __restrict__ outw, int ka, int K) {
  int k = blockIdx.x * blockDim.x + threadIdx.x;
  int n = blockIdx.y;
  if (k >= K) return;
  int kb = K - ka;
  float v = (k < ka) ? wa[(size_t)n * ka + k]
                     : wb[(size_t)n * kb + (k - ka)];
  outw[(size_t)n * K + k] = f2bf(v);
}

__global__ void init_state(const float* __restrict__ h0, const float* __restrict__ c0,
                           unsigned short* __restrict__ hb0, unsigned short* __restrict__ hb1,
                           float* __restrict__ cws) {
  int i = blockIdx.x * blockDim.x + threadIdx.x;
  if (i < BH) {
    hb0[i] = f2bf(h0[i]);
    hb1[i] = f2bf(h0[BH + i]);
    cws[i] = c0[i];
    cws[BH + i] = c0[BH + i];
  }
}

// One LSTM cell step. gates[128,8192] = A[128,K] @ Wcat^T + b; A = concat(a0|a1).
// Grid 512, 2 WGs/CU (TLP across barriers). WG owns 4 h-cols (16 gate-cols =
// one MFMA N-tile). Wave wv owns rows [wv*32, wv*32+32).
// A: direct global->register, 4 named sets, 4-ahead. B: LDS ring 8 x 2KB,
// staged 7 ahead (all 4 waves, lanes<32 -> per-wave vmcnt uniform), XOR-swizzled.
template<int K, int KSPLIT>
static __device__ __forceinline__ void lstm_step_body(
    unsigned short (*Bbuf)[16 * 64],
    const unsigned short* __restrict__ a0,   // [128][KSPLIT] row-major
    const unsigned short* __restrict__ a1,   // [128][H_SZ] row-major
    const unsigned short* __restrict__ w,    // [NG][K] bf16
    const float* __restrict__ bias,          // [NG] fp32
    float* __restrict__ c,                   // [B][H] fp32, in-place (WG-private cols)
    unsigned short* __restrict__ hout,       // [B][H] bf16
    float* __restrict__ fout,                // optional [B][H] fp32
    int tid, int lane, int wv, int n0)
{
  constexpr int KT = K >> 6;   // 48 or 64, divisible by 4
  f32x4 acc[2] = {};

  const unsigned short* r0p[2];
  const unsigned short* r1p[2];
#pragma unroll
  for (int rt = 0; rt < 2; ++rt) {
    int row = wv * 32 + rt * 16 + (lane & 15);
    r0p[rt] = a0 + (size_t)row * KSPLIT;
    r1p[rt] = a1 + (size_t)row * H_SZ;
  }
  const int klo = (lane >> 4) << 3;   // lane-group k offset (elems)

  auto loadA = [&](int kt, bf16x8 (&A)[2][2]) {
    const int kb = kt << 6;
    const bool sA = kb < KSPLIT;     // tiles never straddle (KSPLIT % 64 == 0)
    const int off = (sA ? kb : kb - KSPLIT) + klo;
#pragma unroll
    for (int rt = 0; rt < 2; ++rt) {
      const unsigned short* bp = (sA ? r0p[rt] : r1p[rt]) + off;
      A[rt][0] = *(const bf16x8*)(bp);
      A[rt][1] = *(const bf16x8*)(bp + 32);
    }
  };

  // B-tile 16 gate-rows x 64 k = 2KB = 128 x 16B chunks; each wave stages 32
  // (lanes<32). Wave wv covers rows wv*4..wv*4+3; LDS dest base + lane*16.
  auto stageB = [&](int kt) {
    const int kb = kt << 6;
    if (lane < 32) {
      int cid = wv * 32 + lane;                      // 0..127
      int nl  = cid >> 3;                            // gate-row 0..15
      int chs = (cid & 7) ^ (nl & 7);                // pre-swizzled source chunk
      int nn  = ((nl >> 2) << 11) + n0 + (nl & 3);   // gate*2048 + hcol
      const unsigned short* src = w + (size_t)nn * K + kb + (chs << 3);
      async_load16(src, &Bbuf[kt & 7][wv * 256]);
    }
  };

  auto iter = [&](int kt, bf16x8 (&A)[2][2]) {
    if (kt + 7 < KT) stageB(kt + 7);                 // issue stage early
    const int bq = kt & 7;
#pragma unroll
    for (int kkk = 0; kkk < 2; ++kkk) {
      int nl = lane & 15;
      int ch = kkk * 4 + (lane >> 4);
      bf16x8 bfr = *(const bf16x8*)&Bbuf[bq][nl * 64 + ((ch ^ (nl & 7)) << 3)];
#pragma unroll
      for (int rt = 0; rt < 2; ++rt)
        acc[rt] = __builtin_amdgcn_mfma_f32_16x16x32_bf16(A[rt][kkk], bfr, acc[rt], 0, 0, 0);
    }
    if (kt + 4 < KT) loadA(kt + 4, A);               // refill own named set post-use
    // Ladder: retire own B(kt+1) before the barrier (in-order vmcnt count:
    // min(6,rem-1) later stageB + 4 * #loadA issued after it).
    int rem = KT - 1 - kt;
    if (rem >= 7)      asm volatile("s_waitcnt vmcnt(34)" ::: "memory");
    else if (rem == 6) asm volatile("s_waitcnt vmcnt(33)" ::: "memory");
    else if (rem == 5) asm volatile("s_waitcnt vmcnt(32)" ::: "memory");
    else if (rem == 4) asm volatile("s_waitcnt vmcnt(31)" ::: "memory");
    else if (rem == 3) asm volatile("s_waitcnt vmcnt(26)" ::: "memory");
    else if (rem == 2) asm volatile("s_waitcnt vmcnt(21)" ::: "memory");
    else if (rem == 1) asm volatile("s_waitcnt vmcnt(16)" ::: "memory");
    wg_barrier_pinned();   // rem==0: plain pinned barrier (reads already consumed)
  };

  // Drain any prior-body epilogue vmem (stores/loads share the vmcnt FIFO;
  // prologue counts below assume an empty queue).
  asm volatile("s_waitcnt vmcnt(0)" ::: "memory");

  bf16x8 A0[2][2], A1[2][2], A2[2][2], A3[2][2];
  // Prologue queue: B0,A0x4,B1,A1x4,B2,A2x4,B3,A3x4,B4,B5,B6 = 23 ops; retire B0.
  stageB(0); loadA(0, A0);
  stageB(1); loadA(1, A1);
  stageB(2); loadA(2, A2);
  stageB(3); loadA(3, A3);
  stageB(4); stageB(5); stageB(6);
  asm volatile("s_waitcnt vmcnt(22)" ::: "memory");
  wg_barrier_pinned();

  for (int kt = 0; kt < KT; kt += 4) {
    iter(kt,     A0);
    iter(kt + 1, A1);
    iter(kt + 2, A2);
    iter(kt + 3, A3);
  }

  // Epilogue. C/D map: col = lane&15 -> gate gp=(lane>>2)&3, hc=n0+(lane&3);
  // row = wv*32 + rt*16 + ((lane>>4)<<2) + r. Gates for one cell live in the
  // lane quad {l, l^4, l^8, l^12}; gather via 3 shfl_xor, then each lane
  // finalizes cells m in {2gp, 2gp+1} (m = rt*4+r) with static indices.
  const int hc = n0 + (lane & 3);
  const float bi  = bias[hc];
  const float bff = bias[H_SZ + hc];
  const float bg  = bias[2 * H_SZ + hc];
  const float bo  = bias[3 * H_SZ + hc];
  const int gp = (lane >> 2) & 3;

  float v[8], s4[8], s8[8], s12[8];
#pragma unroll
  for (int m = 0; m < 8; ++m) {
    float x0 = acc[m >> 2][m & 3];
    v[m]   = x0;
    s4[m]  = __shfl_xor(x0, 4);
    s8[m]  = __shfl_xor(x0, 8);
    s12[m] = __shfl_xor(x0, 12);
  }

  auto fin = [&](int m, float gi, float gf, float gg, float go) {
    int row = wv * 32 + (m >> 2) * 16 + ((lane >> 4) << 2) + (m & 3);
    size_t idx = (size_t)row * H_SZ + hc;
    float iv = sigm(gi + bi);
    float fv = sigm(gf + bff);
    float gv = tanh_(gg + bg);
    float ov = sigm(go + bo);
    float cn = fv * c[idx] + iv * gv;
    c[idx] = cn;
    float hn = ov * tanh_(cn);
    hout[idx] = f2bf(hn);
    if (fout) fout[idx] = hn;
  };
  // gate k held in shuffle-slot (k ^ gp): 0->v, 1->s4, 2->s8, 3->s12
  if (gp == 0)      { fin(0, v[0],  s4[0],  s8[0],  s12[0]); fin(1, v[1],  s4[1],  s8[1],  s12[1]); }
  else if (gp == 1) { fin(2, s4[2], v[2],   s12[2], s8[2]);  fin(3, s4[3], v[3],   s12[3], s8[3]);  }
  else if (gp == 2) { fin(4, s8[4], s12[4], v[4],   s4[4]);  fin(5, s8[5], s12[5], v[5],   s4[5]);  }
  else              { fin(6, s12[6],s8[6],  s4[6],  v[6]);   fin(7, s12[7],s8[7],  s4[7],  v[7]);   }
}

// Single step (edges of the schedule).
template<int K, int KSPLIT>
__global__ __launch_bounds__(256) void lstm_one(
    const unsigned short* __restrict__ a0, const unsigned short* __restrict__ a1,
    const unsigned short* __restrict__ w,  const float* __restrict__ bias,
    float* __restrict__ c, unsigned short* __restrict__ hout, float* __restrict__ fout)
{
  __shared__ __align__(16) unsigned short Bbuf[8][16 * 64];   // 16 KB
  const int tid = threadIdx.x, lane = tid & 63, wv = tid >> 6, n0 = blockIdx.x << 2;
  lstm_step_body<K, KSPLIT>(Bbuf, a0, a1, w, bias, c, hout, fout, tid, lane, wv, n0);
}

// Fused pair: L1(t) then L0(t+1). Bodies independent (read only buffers
// published at the preceding dispatch boundary; writes read only after the
// next boundary) -> no internal grid sync; pipelines overlap at the seam.
template<int K1, int KS1, int K2, int KS2>
__global__ __launch_bounds__(256) void lstm_pair(
    const unsigned short* __restrict__ a0_1, const unsigned short* __restrict__ a1_1,
    const unsigned short* __restrict__ w1,   const float* __restrict__ bias1,
    float* __restrict__ c1, unsigned short* __restrict__ h1out,
    const unsigned short* __restrict__ a0_2, const unsigned short* __restrict__ a1_2,
    const unsigned short* __restrict__ w2,   const float* __restrict__ bias2,
    float* __restrict__ c2, unsigned short* __restrict__ h2out)
{
  __shared__ __align__(16) unsigned short Bbuf[8][16 * 64];   // 16 KB
  const int tid = threadIdx.x, lane = tid & 63, wv = tid >> 6, n0 = blockIdx.x << 2;
  lstm_step_body<K1, KS1>(Bbuf, a0_1, a1_1, w1, bias1, c1, h1out, nullptr, tid, lane, wv, n0);
  lstm_step_body<K2, KS2>(Bbuf, a0_2, a1_2, w2, bias2, c2, h2out, nullptr, tid, lane, wv, n0);
}

extern "C" void kernel_launch(void* const* d_in, const int* in_sizes, int n_in,
                              void* d_out, int out_size, void* d_ws, size_t ws_size,
                              hipStream_t stream) {
  (void)in_sizes; (void)n_in; (void)out_size; (void)ws_size;
  const float* x    = (const float*)d_in[0];
  const float* h0   = (const float*)d_in[1];
  const float* c0   = (const float*)d_in[2];
  const float* Wih0 = (const float*)d_in[3];
  const float* Whh0 = (const float*)d_in[4];
  const float* b0   = (const float*)d_in[5];
  const float* Wih1 = (const float*)d_in[6];
  const float* Whh1 = (const float*)d_in[7];
  const float* b1   = (const float*)d_in[8];
  float* out = (float*)d_out;

  unsigned short* xbf = (unsigned short*)d_ws;                     // 512*128*1024 bf16
  unsigned short* Wc0 = xbf + (size_t)T_STEPS * B_SZ * DIN;        // 8192*3072
  unsigned short* Wc1 = Wc0 + (size_t)NG * 3072;                   // 8192*4096
  unsigned short* hb0 = Wc1 + (size_t)NG * 4096;                   // 2 * BH (ping-pong)
  unsigned short* hb1 = hb0 + 2 * (size_t)BH;                      // 2 * BH
  float*          cws = (float*)(hb1 + 2 * (size_t)BH);            // 2 * BH fp32

  cvt_x_bf16<<<dim3(4096), dim3(256), 0, stream>>>(
      (const float4*)x, (ushort4*)xbf, T_STEPS * B_SZ * DIN / 4);
  build_wcat<<<dim3(12, NG), dim3(256), 0, stream>>>(Wih0, Whh0, Wc0, DIN, 3072);
  build_wcat<<<dim3(16, NG), dim3(256), 0, stream>>>(Wih1, Whh1, Wc1, H_SZ, 4096);
  init_state<<<dim3(BH / 256), dim3(256), 0, stream>>>(h0, c0, hb0, hb1, cws);

  // Schedule: L0(0); { L1(t) + L0(t+1) } t=0..510; L1(511)->out.
  // h slots: L0(t) reads hb0 slot[t&1], writes slot[(t+1)&1];
  //          L1(t) reads hb0 slot[(t+1)&1] + hb1 slot[t&1], writes hb1 slot[(t+1)&1].
  lstm_one<3072, 1024><<<dim3(512), dim3(256), 0, stream>>>(
      xbf, hb0 + 0, Wc0, b0, cws, hb0 + BH, nullptr);

  for (int t = 0; t < T_STEPS - 1; ++t) {
    const unsigned short* h0cur = hb0 + (size_t)((t + 1) & 1) * BH;
    lstm_pair<4096, 2048, 3072, 1024><<<dim3(512), dim3(256), 0, stream>>>(
        /*L1(t)*/   h0cur, hb1 + (size_t)(t & 1) * BH, Wc1, b1,
                    cws + BH, hb1 + (size_t)((t + 1) & 1) * BH,
        /*L0(t+1)*/ xbf + (size_t)(t + 1) * B_SZ * DIN, h0cur, Wc0, b0,
                    cws, hb0 + (size_t)(t & 1) * BH);
  }
  // L1(511): reads hb0 slot0, hb1 slot1; writes hb1 slot0 + fp32 out.
  lstm_one<4096, 2048><<<dim3(512), dim3(256), 0, stream>>>(
      hb0 + 0, hb1 + BH, Wc1, b1, cws + BH, hb1 + 0, out);
}

// Round 9
// 22297.559 us; speedup vs baseline: 2.6246x; 2.6246x over previous
//
#include <hip/hip_runtime.h>
#include <stdint.h>
#include <stddef.h>

#define T_STEPS 512
#define B_SZ    128
#define DIN     1024
#define H_SZ    2048
#define NG      8192            // 4*H
#define BH      (B_SZ * H_SZ)   // 262144

typedef __attribute__((ext_vector_type(8))) short bf16x8;
typedef __attribute__((ext_vector_type(4))) float f32x4;

static __device__ __forceinline__ unsigned short f2bf(float x) {
  unsigned int u = __float_as_uint(x);
  u += 0x7fffu + ((u >> 16) & 1u);   // RNE; inputs finite
  return (unsigned short)(u >> 16);
}

static __device__ __forceinline__ float sigm(float x) {
  return 1.0f / (1.0f + __expf(-x));
}
static __device__ __forceinline__ float tanh_(float x) {
  float e = __expf(-2.0f * fabsf(x));  // in (0,1], no overflow
  float t = (1.0f - e) / (1.0f + e);
  return x < 0.0f ? -t : t;
}

// global -> LDS async copy, 16B per lane. LDS dest is wave-uniform base;
// HW writes lane l at ldst + l*16. Global src IS per-lane (swizzle there).
static __device__ __forceinline__ void async_load16(const void* gsrc, void* ldst) {
  __builtin_amdgcn_global_load_lds(
      (__attribute__((address_space(1))) void*)(const_cast<void*>(gsrc)),
      (__attribute__((address_space(3))) void*)ldst,
      16, 0, 0);
}

// Barrier that memory ops cannot be compiler-moved across (rd4's NaN fix).
static __device__ __forceinline__ void wg_barrier_pinned() {
  __builtin_amdgcn_s_barrier();
  asm volatile("" ::: "memory");
  __builtin_amdgcn_sched_barrier(0);
}

__global__ void cvt_x_bf16(const float4* __restrict__ in, ushort4* __restrict__ out, int n4) {
  int i = blockIdx.x * blockDim.x + threadIdx.x;
  int st = gridDim.x * blockDim.x;
  for (; i < n4; i += st) {
    float4 v = in[i];
    ushort4 o;
    o.x = f2bf(v.x); o.y = f2bf(v.y); o.z = f2bf(v.z); o.w = f2bf(v.w);
    out[i] = o;
  }
}

__global__ void build_wcat(const float* __restrict__ wa, const float* __restrict__ wb,
                           unsigned short* __restrict__ outw, int ka, int K) {
  int k = blockIdx.x * blockDim.x + threadIdx.x;
  int n = blockIdx.y;
  if (k >= K) return;
  int kb = K - ka;
  float v = (k < ka) ? wa[(size_t)n * ka + k]
                     : wb[(size_t)n * kb + (k - ka)];
  outw[(size_t)n * K + k] = f2bf(v);
}

__global__ void init_state(const float* __restrict__ h0, const float* __restrict__ c0,
                           unsigned short* __restrict__ hb0, unsigned short* __restrict__ hb1,
                           float* __restrict__ cws) {
  int i = blockIdx.x * blockDim.x + threadIdx.x;
  if (i < BH) {
    hb0[i] = f2bf(h0[i]);
    hb1[i] = f2bf(h0[BH + i]);
    cws[i] = c0[i];
    cws[BH + i] = c0[BH + i];
  }
}

// One LSTM cell step. gates[128,8192] = A[128,K] @ Wcat^T + b; A = concat(a0|a1).
// WG = 128 rows x 64 gate-cols (16 h-cols; each lane holds all 4 gates of a
// cell -> lane-local epilogue). Wave wv owns rows [wv*32, wv*32+32).
// A: direct global->register, 4 named sets, 4-ahead.
// B: LDS ring 8 x 8KB, staged 7 ahead via global_load_lds, XOR-swizzled.
// Per-wave VMEM per iter: 2 stageB-chunks + 4 loadA.
template<int K, int KSPLIT>
static __device__ __forceinline__ void lstm_step_body(
    unsigned short (*Bbuf)[64 * 64],
    const unsigned short* __restrict__ a0,   // [128][KSPLIT] row-major
    const unsigned short* __restrict__ a1,   // [128][H_SZ] row-major
    const unsigned short* __restrict__ w,    // [NG][K] bf16
    const float* __restrict__ bias,          // [NG] fp32
    float* __restrict__ c,                   // [B][H] fp32, in-place (WG-private cols)
    unsigned short* __restrict__ hout,       // [B][H] bf16
    float* __restrict__ fout,                // optional [B][H] fp32
    int tid, int lane, int wv, int n0)
{
  constexpr int KT = K >> 6;   // 48 or 64, divisible by 4
  f32x4 acc[2][4] = {};

  const unsigned short* r0p[2];
  const unsigned short* r1p[2];
#pragma unroll
  for (int rt = 0; rt < 2; ++rt) {
    int row = wv * 32 + rt * 16 + (lane & 15);
    r0p[rt] = a0 + (size_t)row * KSPLIT;
    r1p[rt] = a1 + (size_t)row * H_SZ;
  }
  const int klo = (lane >> 4) << 3;   // lane-group k offset (elems)

  auto loadA = [&](int kt, bf16x8 (&A)[2][2]) {
    const int kb = kt << 6;
    const bool sA = kb < KSPLIT;     // tiles never straddle (KSPLIT % 64 == 0)
    const int off = (sA ? kb : kb - KSPLIT) + klo;
#pragma unroll
    for (int rt = 0; rt < 2; ++rt) {
      const unsigned short* bp = (sA ? r0p[rt] : r1p[rt]) + off;
      A[rt][0] = *(const bf16x8*)(bp);
      A[rt][1] = *(const bf16x8*)(bp + 32);
    }
  };

  // B-tile 64 gate-rows x 64 k = 8KB = 512 x 16B chunks; 2 per thread.
  auto stageB = [&](int kt) {
    const int kb = kt << 6;
#pragma unroll
    for (int it = 0; it < 2; ++it) {
      int cid = it * 256 + tid;
      int nl  = cid >> 3;                            // gate-row 0..63
      int chs = (cid & 7) ^ (nl & 7);                // pre-swizzled source chunk
      int nn  = ((nl >> 4) << 11) + n0 + (nl & 15);  // gate*2048 + hcol
      const unsigned short* src = w + (size_t)nn * K + kb + (chs << 3);
      async_load16(src, &Bbuf[kt & 7][(it * 256 + wv * 64) * 8]);
    }
  };

  auto iter = [&](int kt, bf16x8 (&A)[2][2]) {
    if (kt + 7 < KT) stageB(kt + 7);                 // issue stage early
    const int bq = kt & 7;
#pragma unroll
    for (int kkk = 0; kkk < 2; ++kkk) {
      const int ch = kkk * 4 + (lane >> 4);
      const int cswz = (ch ^ (lane & 7)) << 3;       // (nl&7) == lane&7 for all ct
      bf16x8 bfr[4];
#pragma unroll
      for (int ct = 0; ct < 4; ++ct)
        bfr[ct] = *(const bf16x8*)&Bbuf[bq][(ct * 16 + (lane & 15)) * 64 + cswz];
#pragma unroll
      for (int rt = 0; rt < 2; ++rt)
#pragma unroll
        for (int ct = 0; ct < 4; ++ct)
          acc[rt][ct] = __builtin_amdgcn_mfma_f32_16x16x32_bf16(A[rt][kkk], bfr[ct], acc[rt][ct], 0, 0, 0);
    }
    if (kt + 4 < KT) loadA(kt + 4, A);               // refill own named set post-use
    // Ladder: retire own B(kt+1) (2 chunks) before the barrier. In-order vmcnt:
    // ops issued after it = 4 + sum over last 6 iters of (2 if SB valid)+(4 if LA valid).
    int rem = KT - 1 - kt;
    if (rem >= 7)      asm volatile("s_waitcnt vmcnt(40)" ::: "memory");
    else if (rem == 6) asm volatile("s_waitcnt vmcnt(38)" ::: "memory");
    else if (rem == 5) asm volatile("s_waitcnt vmcnt(36)" ::: "memory");
    else if (rem == 4) asm volatile("s_waitcnt vmcnt(34)" ::: "memory");
    else if (rem == 3) asm volatile("s_waitcnt vmcnt(28)" ::: "memory");
    else if (rem == 2) asm volatile("s_waitcnt vmcnt(22)" ::: "memory");
    else if (rem == 1) asm volatile("s_waitcnt vmcnt(16)" ::: "memory");
    wg_barrier_pinned();   // rem==0: plain pinned barrier (reads already consumed)
  };

  // Drain prior-body epilogue vmem (stores/loads share the vmcnt FIFO).
  asm volatile("s_waitcnt vmcnt(0)" ::: "memory");

  bf16x8 A0[2][2], A1[2][2], A2[2][2], A3[2][2];
  // Prologue queue: B0x2,A0x4,B1x2,A1x4,B2x2,A2x4,B3x2,A3x4,B4x2,B5x2,B6x2 = 30.
  stageB(0); loadA(0, A0);
  stageB(1); loadA(1, A1);
  stageB(2); loadA(2, A2);
  stageB(3); loadA(3, A3);
  stageB(4); stageB(5); stageB(6);
  asm volatile("s_waitcnt vmcnt(28)" ::: "memory");   // retire B0
  wg_barrier_pinned();

  for (int kt = 0; kt < KT; kt += 4) {
    iter(kt,     A0);
    iter(kt + 1, A1);
    iter(kt + 2, A2);
    iter(kt + 3, A3);
  }

  // Epilogue (lane-local, rd1-verified). C/D map: col(nl)=lane&15 -> gate=ct,
  // hc=n0+(lane&15); row = wv*32 + rt*16 + (lane>>4)*4 + r.
  const int hc = n0 + (lane & 15);
  const float bi  = bias[hc];
  const float bff = bias[H_SZ + hc];
  const float bg  = bias[2 * H_SZ + hc];
  const float bo  = bias[3 * H_SZ + hc];

#pragma unroll
  for (int rt = 0; rt < 2; ++rt) {
#pragma unroll
    for (int r = 0; r < 4; ++r) {
      int row = wv * 32 + rt * 16 + ((lane >> 4) << 2) + r;
      size_t idx = (size_t)row * H_SZ + hc;
      float iv = sigm(acc[rt][0][r] + bi);
      float fv = sigm(acc[rt][1][r] + bff);
      float gv = tanh_(acc[rt][2][r] + bg);
      float ov = sigm(acc[rt][3][r] + bo);
      float cn = fv * c[idx] + iv * gv;
      c[idx] = cn;
      float hn = ov * tanh_(cn);
      hout[idx] = f2bf(hn);
      if (fout) fout[idx] = hn;
    }
  }
}

// Single step (edges of the schedule). Grid 128 (16 h-cols per WG).
template<int K, int KSPLIT>
__global__ __launch_bounds__(256) void lstm_one(
    const unsigned short* __restrict__ a0, const unsigned short* __restrict__ a1,
    const unsigned short* __restrict__ w,  const float* __restrict__ bias,
    float* __restrict__ c, unsigned short* __restrict__ hout, float* __restrict__ fout)
{
  __shared__ __align__(16) unsigned short Bbuf[8][64 * 64];   // 64 KB
  const int tid = threadIdx.x, lane = tid & 63, wv = tid >> 6, n0 = blockIdx.x << 4;
  lstm_step_body<K, KSPLIT>(Bbuf, a0, a1, w, bias, c, hout, fout, tid, lane, wv, n0);
}

// Layer-split pair: grid 256. WGs 0..127 run L1(t), WGs 128..255 run L0(t+1)
// CONCURRENTLY (independent: both read only buffers published at the
// preceding dispatch boundary; writes are disjoint and read only after the
// next boundary). Wall per pair = max(L1, L0) instead of L1 + L0.
template<int K1, int KS1, int K2, int KS2>
__global__ __launch_bounds__(256) void lstm_pair(
    const unsigned short* __restrict__ a0_1, const unsigned short* __restrict__ a1_1,
    const unsigned short* __restrict__ w1,   const float* __restrict__ bias1,
    float* __restrict__ c1, unsigned short* __restrict__ h1out,
    const unsigned short* __restrict__ a0_2, const unsigned short* __restrict__ a1_2,
    const unsigned short* __restrict__ w2,   const float* __restrict__ bias2,
    float* __restrict__ c2, unsigned short* __restrict__ h2out)
{
  __shared__ __align__(16) unsigned short Bbuf[8][64 * 64];   // 64 KB
  const int tid = threadIdx.x, lane = tid & 63, wv = tid >> 6;
  if (blockIdx.x < 128) {
    const int n0 = blockIdx.x << 4;
    lstm_step_body<K1, KS1>(Bbuf, a0_1, a1_1, w1, bias1, c1, h1out, nullptr, tid, lane, wv, n0);
  } else {
    const int n0 = (blockIdx.x - 128) << 4;
    lstm_step_body<K2, KS2>(Bbuf, a0_2, a1_2, w2, bias2, c2, h2out, nullptr, tid, lane, wv, n0);
  }
}

extern "C" void kernel_launch(void* const* d_in, const int* in_sizes, int n_in,
                              void* d_out, int out_size, void* d_ws, size_t ws_size,
                              hipStream_t stream) {
  (void)in_sizes; (void)n_in; (void)out_size; (void)ws_size;
  const float* x    = (const float*)d_in[0];
  const float* h0   = (const float*)d_in[1];
  const float* c0   = (const float*)d_in[2];
  const float* Wih0 = (const float*)d_in[3];
  const float* Whh0 = (const float*)d_in[4];
  const float* b0   = (const float*)d_in[5];
  const float* Wih1 = (const float*)d_in[6];
  const float* Whh1 = (const float*)d_in[7];
  const float* b1   = (const float*)d_in[8];
  float* out = (float*)d_out;

  unsigned short* xbf = (unsigned short*)d_ws;                     // 512*128*1024 bf16
  unsigned short* Wc0 = xbf + (size_t)T_STEPS * B_SZ * DIN;        // 8192*3072
  unsigned short* Wc1 = Wc0 + (size_t)NG * 3072;                   // 8192*4096
  unsigned short* hb0 = Wc1 + (size_t)NG * 4096;                   // 2 * BH (ping-pong)
  unsigned short* hb1 = hb0 + 2 * (size_t)BH;                      // 2 * BH
  float*          cws = (float*)(hb1 + 2 * (size_t)BH);            // 2 * BH fp32

  cvt_x_bf16<<<dim3(4096), dim3(256), 0, stream>>>(
      (const float4*)x, (ushort4*)xbf, T_STEPS * B_SZ * DIN / 4);
  build_wcat<<<dim3(12, NG), dim3(256), 0, stream>>>(Wih0, Whh0, Wc0, DIN, 3072);
  build_wcat<<<dim3(16, NG), dim3(256), 0, stream>>>(Wih1, Whh1, Wc1, H_SZ, 4096);
  init_state<<<dim3(BH / 256), dim3(256), 0, stream>>>(h0, c0, hb0, hb1, cws);

  // Schedule: L0(0); { L1(t) || L0(t+1) } t=0..510; L1(511)->out.
  // h slots: L0(t) reads hb0 slot[t&1], writes slot[(t+1)&1];
  //          L1(t) reads hb0 slot[(t+1)&1] + hb1 slot[t&1], writes hb1 slot[(t+1)&1].
  lstm_one<3072, 1024><<<dim3(128), dim3(256), 0, stream>>>(
      xbf, hb0 + 0, Wc0, b0, cws, hb0 + BH, nullptr);

  for (int t = 0; t < T_STEPS - 1; ++t) {
    const unsigned short* h0cur = hb0 + (size_t)((t + 1) & 1) * BH;
    lstm_pair<4096, 2048, 3072, 1024><<<dim3(256), dim3(256), 0, stream>>>(
        /*L1(t)*/   h0cur, hb1 + (size_t)(t & 1) * BH, Wc1, b1,
                    cws + BH, hb1 + (size_t)((t + 1) & 1) * BH,
        /*L0(t+1)*/ xbf + (size_t)(t + 1) * B_SZ * DIN, h0cur, Wc0, b0,
                    cws, hb0 + (size_t)(t & 1) * BH);
  }
  // L1(511): reads hb0 slot0, hb1 slot1; writes hb1 slot0 + fp32 out.
  lstm_one<4096, 2048><<<dim3(128), dim3(256), 0, stream>>>(
      hb0 + 0, hb1 + BH, Wc1, b1, cws + BH, hb1 + 0, out);
}

// Round 10
// 19929.292 us; speedup vs baseline: 2.9365x; 1.1188x over previous
//
#include <hip/hip_runtime.h>
#include <stdint.h>
#include <stddef.h>

#define T_STEPS 512
#define B_SZ    128
#define DIN     1024
#define H_SZ    2048
#define NG      8192            // 4*H
#define BH      (B_SZ * H_SZ)   // 262144

typedef __attribute__((ext_vector_type(8))) short bf16x8;
typedef __attribute__((ext_vector_type(4))) float f32x4;

static __device__ __forceinline__ unsigned short f2bf(float x) {
  unsigned int u = __float_as_uint(x);
  u += 0x7fffu + ((u >> 16) & 1u);   // RNE; inputs finite
  return (unsigned short)(u >> 16);
}

static __device__ __forceinline__ float sigm(float x) {
  return 1.0f / (1.0f + __expf(-x));
}
static __device__ __forceinline__ float tanh_(float x) {
  float e = __expf(-2.0f * fabsf(x));  // in (0,1], no overflow
  float t = (1.0f - e) / (1.0f + e);
  return x < 0.0f ? -t : t;
}

// global -> LDS async copy, 16B per lane. LDS dest is wave-uniform base;
// HW writes lane l at ldst + l*16. Global src IS per-lane (swizzle there).
static __device__ __forceinline__ void async_load16(const void* gsrc, void* ldst) {
  __builtin_amdgcn_global_load_lds(
      (__attribute__((address_space(1))) void*)(const_cast<void*>(gsrc)),
      (__attribute__((address_space(3))) void*)ldst,
      16, 0, 0);
}

// Barrier that memory ops cannot be compiler-moved across (rd4's NaN fix).
static __device__ __forceinline__ void wg_barrier_pinned() {
  __builtin_amdgcn_s_barrier();
  asm volatile("" ::: "memory");
  __builtin_amdgcn_sched_barrier(0);
}

__global__ void cvt_x_bf16(const float4* __restrict__ in, ushort4* __restrict__ out, int n4) {
  int i = blockIdx.x * blockDim.x + threadIdx.x;
  int st = gridDim.x * blockDim.x;
  for (; i < n4; i += st) {
    float4 v = in[i];
    ushort4 o;
    o.x = f2bf(v.x); o.y = f2bf(v.y); o.z = f2bf(v.z); o.w = f2bf(v.w);
    out[i] = o;
  }
}

__global__ void build_wcat(const float* __restrict__ wa, const float* __restrict__ wb,
                           unsigned short* __restrict__ outw, int ka, int K) {
  int k = blockIdx.x * blockDim.x + threadIdx.x;
  int n = blockIdx.y;
  if (k >= K) return;
  int kb = K - ka;
  float v = (k < ka) ? wa[(size_t)n * ka + k]
                     : wb[(size_t)n * kb + (k - ka)];
  outw[(size_t)n * K + k] = f2bf(v);
}

__global__ void init_state(const float* __restrict__ h0, const float* __restrict__ c0,
                           unsigned short* __restrict__ hb0, unsigned short* __restrict__ hb1,
                           float* __restrict__ cws) {
  int i = blockIdx.x * blockDim.x + threadIdx.x;
  if (i < BH) {
    hb0[i] = f2bf(h0[i]);
    hb1[i] = f2bf(h0[BH + i]);
    cws[i] = c0[i];
    cws[BH + i] = c0[BH + i];
  }
}

// One LSTM cell step. gates[128,8192] = A[128,K] @ Wcat^T + b; A = concat(a0|a1).
// WG tile = 64 rows x 128 gate-cols (32 h-cols). Within a layer: 128 WGs =
// 2 row-blocks (mb) x 64 col-blocks (cb). Wave wv owns rows mb*64+wv*16..+16.
// Lane holds all 4 gates: acc[ct], ct = gate*2 + p (p = hcol half) -> lane-local
// epilogue. A: direct global->register, 4 named sets, 4-ahead.
// B: LDS ring 4 x 16KB, staged 3 ahead via global_load_lds, XOR-swizzled.
// Per-wave VMEM per iter: 4 stageB chunks + 2 loadA.
template<int K, int KSPLIT>
static __device__ __forceinline__ void lstm_step_body(
    unsigned short (*Bbuf)[128 * 64],
    const unsigned short* __restrict__ a0,   // [128][KSPLIT] row-major
    const unsigned short* __restrict__ a1,   // [128][H_SZ] row-major
    const unsigned short* __restrict__ w,    // [NG][K] bf16
    const float* __restrict__ bias,          // [NG] fp32
    float* __restrict__ c,                   // [B][H] fp32, in-place (tile-private)
    unsigned short* __restrict__ hout,       // [B][H] bf16
    float* __restrict__ fout,                // optional [B][H] fp32
    int tid, int lane, int wv, int mb, int n0h)   // n0h = cb*32 (h-col base)
{
  constexpr int KT = K >> 6;   // 48 or 64, divisible by 4
  f32x4 acc[8] = {};

  const int arow = mb * 64 + wv * 16 + (lane & 15);
  const unsigned short* r0p = a0 + (size_t)arow * KSPLIT;
  const unsigned short* r1p = a1 + (size_t)arow * H_SZ;
  const int klo = (lane >> 4) << 3;   // lane-group k offset (elems)

  auto loadA = [&](int kt, bf16x8 (&A)[2]) {
    const int kb = kt << 6;
    const bool sA = kb < KSPLIT;     // tiles never straddle (KSPLIT % 64 == 0)
    const unsigned short* bp = (sA ? r0p : r1p) + (sA ? kb : kb - KSPLIT) + klo;
    A[0] = *(const bf16x8*)(bp);
    A[1] = *(const bf16x8*)(bp + 32);
  };

  // B-tile 128 gate-rows x 64 k = 16KB = 1024 x 16B chunks; 4 per thread.
  // gate-row nl -> wcat row nn = (nl>>5)*2048 + n0h + (nl&31).
  auto stageB = [&](int kt) {
    const int kb = kt << 6;
#pragma unroll
    for (int it = 0; it < 4; ++it) {
      int cid = it * 256 + tid;
      int nl  = cid >> 3;                            // gate-row 0..127
      int chs = (cid & 7) ^ (nl & 7);                // pre-swizzled source chunk
      int nn  = ((nl >> 5) << 11) + n0h + (nl & 31);
      const unsigned short* src = w + (size_t)nn * K + kb + (chs << 3);
      async_load16(src, &Bbuf[kt & 3][(it * 256 + wv * 64) * 8]);
    }
  };

  auto iter = [&](int kt, bf16x8 (&A)[2]) {
    if (kt + 3 < KT) stageB(kt + 3);                 // issue stage early
    const int bq = kt & 3;
#pragma unroll
    for (int kkk = 0; kkk < 2; ++kkk) {
      const int ch = kkk * 4 + (lane >> 4);
      const int cswz = (ch ^ (lane & 7)) << 3;       // (nl&7) == lane&7 for all ct
      bf16x8 bfr[8];
#pragma unroll
      for (int ct = 0; ct < 8; ++ct)
        bfr[ct] = *(const bf16x8*)&Bbuf[bq][(ct * 16 + (lane & 15)) * 64 + cswz];
#pragma unroll
      for (int ct = 0; ct < 8; ++ct)
        acc[ct] = __builtin_amdgcn_mfma_f32_16x16x32_bf16(A[kkk], bfr[ct], acc[ct], 0, 0, 0);
    }
    if (kt + 4 < KT) loadA(kt + 4, A);               // refill own named set post-use
    // Ladder: retire own B(kt+1) (4 chunks) before the barrier. In-order vmcnt:
    // ops issued after it = LA(kt+2)x2 + [SB(kt+2)x4+LA(kt+3)x2] + [SB(kt+3)x4+LA(kt+4)x2].
    int rem = KT - 1 - kt;
    if (rem >= 4)      asm volatile("s_waitcnt vmcnt(14)" ::: "memory");
    else if (rem == 3) asm volatile("s_waitcnt vmcnt(12)" ::: "memory");
    else if (rem == 2) asm volatile("s_waitcnt vmcnt(6)"  ::: "memory");
    else if (rem == 1) asm volatile("s_waitcnt vmcnt(0)"  ::: "memory");
    wg_barrier_pinned();   // rem==0: plain pinned barrier (reads already consumed)
  };

  // Entry guard: prologue counts assume an empty vmcnt FIFO.
  asm volatile("s_waitcnt vmcnt(0)" ::: "memory");

  bf16x8 A0[2], A1[2], A2[2], A3[2];
  // Prologue queue: B0x4,A0x2,B1x4,A1x2,B2x4,A2x2,A3x2 = 20 ops; retire B0 -> 16.
  stageB(0); loadA(0, A0);
  stageB(1); loadA(1, A1);
  stageB(2); loadA(2, A2);
  loadA(3, A3);
  asm volatile("s_waitcnt vmcnt(16)" ::: "memory");
  wg_barrier_pinned();

  for (int kt = 0; kt < KT; kt += 4) {
    iter(kt,     A0);
    iter(kt + 1, A1);
    iter(kt + 2, A2);
    iter(kt + 3, A3);
  }

  // Epilogue (lane-local). C/D map: col(nl)=lane&15 -> nl = ct*16+(lane&15);
  // gate = nl>>5 = ct>>1; hcol = n0h + (ct&1)*16 + (lane&15).
  // row = mb*64 + wv*16 + (lane>>4)*4 + r.
#pragma unroll
  for (int p = 0; p < 2; ++p) {
    const int hc = n0h + p * 16 + (lane & 15);
    const float bi  = bias[hc];
    const float bff = bias[H_SZ + hc];
    const float bg  = bias[2 * H_SZ + hc];
    const float bo  = bias[3 * H_SZ + hc];
#pragma unroll
    for (int r = 0; r < 4; ++r) {
      int row = mb * 64 + wv * 16 + ((lane >> 4) << 2) + r;
      size_t idx = (size_t)row * H_SZ + hc;
      float iv = sigm(acc[p    ][r] + bi);
      float fv = sigm(acc[p + 2][r] + bff);
      float gv = tanh_(acc[p + 4][r] + bg);
      float ov = sigm(acc[p + 6][r] + bo);
      float cn = fv * c[idx] + iv * gv;
      c[idx] = cn;
      float hn = ov * tanh_(cn);
      hout[idx] = f2bf(hn);
      if (fout) fout[idx] = hn;
    }
  }
}

// Single step (edges of the schedule). Grid 128 = 2 mb x 64 cb.
template<int K, int KSPLIT>
__global__ __launch_bounds__(256) void lstm_one(
    const unsigned short* __restrict__ a0, const unsigned short* __restrict__ a1,
    const unsigned short* __restrict__ w,  const float* __restrict__ bias,
    float* __restrict__ c, unsigned short* __restrict__ hout, float* __restrict__ fout)
{
  __shared__ __align__(16) unsigned short Bbuf[4][128 * 64];   // 64 KB
  const int tid = threadIdx.x, lane = tid & 63, wv = tid >> 6;
  const int mb = blockIdx.x >> 6, n0h = (blockIdx.x & 63) << 5;
  lstm_step_body<K, KSPLIT>(Bbuf, a0, a1, w, bias, c, hout, fout, tid, lane, wv, mb, n0h);
}

// Layer-split pair: grid 256. WGs 0..127 run L1(t), WGs 128..255 run L0(t+1)
// CONCURRENTLY (independent: both read only buffers published at the
// preceding dispatch boundary; writes are disjoint and read only after the
// next boundary). Wall per pair = max(L1, L0) instead of L1 + L0.
template<int K1, int KS1, int K2, int KS2>
__global__ __launch_bounds__(256) void lstm_pair(
    const unsigned short* __restrict__ a0_1, const unsigned short* __restrict__ a1_1,
    const unsigned short* __restrict__ w1,   const float* __restrict__ bias1,
    float* __restrict__ c1, unsigned short* __restrict__ h1out,
    const unsigned short* __restrict__ a0_2, const unsigned short* __restrict__ a1_2,
    const unsigned short* __restrict__ w2,   const float* __restrict__ bias2,
    float* __restrict__ c2, unsigned short* __restrict__ h2out)
{
  __shared__ __align__(16) unsigned short Bbuf[4][128 * 64];   // 64 KB
  const int tid = threadIdx.x, lane = tid & 63, wv = tid >> 6;
  if (blockIdx.x < 128) {
    const int mb = blockIdx.x >> 6, n0h = (blockIdx.x & 63) << 5;
    lstm_step_body<K1, KS1>(Bbuf, a0_1, a1_1, w1, bias1, c1, h1out, nullptr, tid, lane, wv, mb, n0h);
  } else {
    const int W = blockIdx.x - 128;
    const int mb = W >> 6, n0h = (W & 63) << 5;
    lstm_step_body<K2, KS2>(Bbuf, a0_2, a1_2, w2, bias2, c2, h2out, nullptr, tid, lane, wv, mb, n0h);
  }
}

extern "C" void kernel_launch(void* const* d_in, const int* in_sizes, int n_in,
                              void* d_out, int out_size, void* d_ws, size_t ws_size,
                              hipStream_t stream) {
  (void)in_sizes; (void)n_in; (void)out_size; (void)ws_size;
  const float* x    = (const float*)d_in[0];
  const float* h0   = (const float*)d_in[1];
  const float* c0   = (const float*)d_in[2];
  const float* Wih0 = (const float*)d_in[3];
  const float* Whh0 = (const float*)d_in[4];
  const float* b0   = (const float*)d_in[5];
  const float* Wih1 = (const float*)d_in[6];
  const float* Whh1 = (const float*)d_in[7];
  const float* b1   = (const float*)d_in[8];
  float* out = (float*)d_out;

  unsigned short* xbf = (unsigned short*)d_ws;                     // 512*128*1024 bf16
  unsigned short* Wc0 = xbf + (size_t)T_STEPS * B_SZ * DIN;        // 8192*3072
  unsigned short* Wc1 = Wc0 + (size_t)NG * 3072;                   // 8192*4096
  unsigned short* hb0 = Wc1 + (size_t)NG * 4096;                   // 2 * BH (ping-pong)
  unsigned short* hb1 = hb0 + 2 * (size_t)BH;                      // 2 * BH
  float*          cws = (float*)(hb1 + 2 * (size_t)BH);            // 2 * BH fp32

  cvt_x_bf16<<<dim3(4096), dim3(256), 0, stream>>>(
      (const float4*)x, (ushort4*)xbf, T_STEPS * B_SZ * DIN / 4);
  build_wcat<<<dim3(12, NG), dim3(256), 0, stream>>>(Wih0, Whh0, Wc0, DIN, 3072);
  build_wcat<<<dim3(16, NG), dim3(256), 0, stream>>>(Wih1, Whh1, Wc1, H_SZ, 4096);
  init_state<<<dim3(BH / 256), dim3(256), 0, stream>>>(h0, c0, hb0, hb1, cws);

  // Schedule: L0(0); { L1(t) || L0(t+1) } t=0..510; L1(511)->out.
  // h slots: L0(t) reads hb0 slot[t&1], writes slot[(t+1)&1];
  //          L1(t) reads hb0 slot[(t+1)&1] + hb1 slot[t&1], writes hb1 slot[(t+1)&1].
  lstm_one<3072, 1024><<<dim3(128), dim3(256), 0, stream>>>(
      xbf, hb0 + 0, Wc0, b0, cws, hb0 + BH, nullptr);

  for (int t = 0; t < T_STEPS - 1; ++t) {
    const unsigned short* h0cur = hb0 + (size_t)((t + 1) & 1) * BH;
    lstm_pair<4096, 2048, 3072, 1024><<<dim3(256), dim3(256), 0, stream>>>(
        /*L1(t)*/   h0cur, hb1 + (size_t)(t & 1) * BH, Wc1, b1,
                    cws + BH, hb1 + (size_t)((t + 1) & 1) * BH,
        /*L0(t+1)*/ xbf + (size_t)(t + 1) * B_SZ * DIN, h0cur, Wc0, b0,
                    cws, hb0 + (size_t)(t & 1) * BH);
  }
  // L1(511): reads hb0 slot0, hb1 slot1; writes hb1 slot0 + fp32 out.
  lstm_one<4096, 2048><<<dim3(128), dim3(256), 0, stream>>>(
      hb0 + 0, hb1 + BH, Wc1, b1, cws + BH, hb1 + 0, out);
}